// Round 12
// baseline (2680.074 us; speedup 1.0000x reference)
//
#include <hip/hip_runtime.h>

#define NPLANES 24
#define IMG 192
#define RW 194        // f16 ring stride in halfs; ring col = 3 + delta-col (pads zero)
#define TSTEPS 926    // wavefront t = 4*i + j

typedef _Float16 h2v   __attribute__((ext_vector_type(2)));
typedef _Float16 f16x8 __attribute__((ext_vector_type(8)));
typedef float    f32x4 __attribute__((ext_vector_type(4)));
typedef __fp16   fp16x2 __attribute__((ext_vector_type(2)));

__device__ __forceinline__ h2v pk(float a, float b) {
  union { fp16x2 p; h2v h; } u;
  u.p = __builtin_amdgcn_cvt_pkrtz(a, b);
  return u.h;
}
__device__ __forceinline__ float fast_tanh(float x) {
  float e = __expf(2.0f * x);
  return 1.0f - 2.0f / (e + 1.0f);
}
// cell slot (0..47) <-> unique row i == cell (mod 48) inside the active window
__device__ __forceinline__ bool cellmap(int t, int cell, int& i, int& j) {
  const int i_min = (t <= 185) ? 0 : ((t - 182) >> 2);
  int i_max = t >> 2; if (i_max > 185) i_max = 185;
  const int k48 = (i_min - cell + 47) / 48;
  i = cell + 48 * k48;
  j = t - 4 * i;
  return (i <= i_max);
}

// One block per plane, 192 threads = 3 waves, p2p sync (spin gates only data of
// age exactly 1). Stale/fresh L1 split: iteration t runs L1 MFMAs for step t+1
// on features with the two age-1 elements (k=44: row-above delta, k=47: own
// delta) ZEROED, into loop-carried acc1. Iteration t+1 completes L1 with a
// rank-2 VALU update from registers. Critical cycle per step: shfl -> 48 fma
// -> 24 tanh -> h1(LDS) -> L2 (6 MFMA) -> L3 (1 MFMA) -> L4 butterfly -> delta.
__launch_bounds__(192, 1)
__global__ void codec_kernel(const float* __restrict__ x,
                             const float* __restrict__ W1g, const float* __restrict__ b1g,
                             const float* __restrict__ W2g, const float* __restrict__ b2g,
                             const float* __restrict__ W3g, const float* __restrict__ b3g,
                             const float* __restrict__ W4g, const float* __restrict__ b4g,
                             float* __restrict__ ws)
{
  __shared__ _Float16 ringH[64 * RW];   // f16 deltas; ring cols 0..2 & >=189 stay 0
  __shared__ _Float16 featA[48 * 72];   // [cell][48 feat | 16 ZERO K-pad | 8 pad]
  __shared__ _Float16 h1A  [48 * 104];  // [cell][96 + 8 ZERO pad]
  __shared__ _Float16 h2A  [48 * 40];   // [cell][24 + 8 ZERO K-pad + 8 pad]
  __shared__ _Float16 w1B  [96 * 72];
  __shared__ _Float16 w2B  [32 * 104];
  __shared__ _Float16 w3B  [16 * 32];
  __shared__ float    mboxF[12];        // [wave][t&3]: masked boundary delta
  __shared__ float    b1L[96], b2L[24], b3L[16], w4F[16], b4L[1];
  __shared__ float    w44L[96], w47L[96];
  __shared__ int      ctrL[3];
  __shared__ float    wsum[3];

  const int tid  = threadIdx.x;
  const int lane = tid & 63;
  const int w    = __builtin_amdgcn_readfirstlane(tid >> 6);
  const int lam  = lane & 15;
  const int quad = lane >> 4;
  const int cell = 16 * w + lam;
  const float* __restrict__ xp = x + (size_t)blockIdx.x * (IMG * IMG);

  // ---- one-time init ----
  { unsigned* z = (unsigned*)ringH; for (int u = tid; u < 64 * RW / 2;  u += 192) z[u] = 0; }
  { unsigned* z = (unsigned*)featA; for (int u = tid; u < 48 * 72 / 2;  u += 192) z[u] = 0; }
  { unsigned* z = (unsigned*)h1A;   for (int u = tid; u < 48 * 104 / 2; u += 192) z[u] = 0; }
  { unsigned* z = (unsigned*)h2A;   for (int u = tid; u < 48 * 40 / 2;  u += 192) z[u] = 0; }
  for (int u = tid; u < 96 * 72; u += 192) {
    int n = u / 72, k = u - n * 72;
    // zero k=44,47 in the MFMA copy: handled by rank-2 in f32 instead
    _Float16 v = (_Float16)0.f;
    if (k < 48 && k != 44 && k != 47) v = (_Float16)W1g[k * 96 + n];
    w1B[u] = v;
  }
  for (int u = tid; u < 32 * 104; u += 192) {
    int n = u / 104, k = u - n * 104;
    w2B[u] = (n < 24 && k < 96) ? (_Float16)W2g[k * 24 + n] : (_Float16)0.f;
  }
  for (int u = tid; u < 16 * 32; u += 192) {
    int n = u / 32, k = u - n * 32;
    w3B[u] = (n < 12 && k < 24) ? (_Float16)W3g[k * 12 + n] : (_Float16)0.f;
  }
  for (int u = tid; u < 96; u += 192) {
    b1L[u]  = b1g[u];
    w44L[u] = W1g[44 * 96 + u];
    w47L[u] = W1g[47 * 96 + u];
  }
  if (tid < 24) b2L[tid] = b2g[tid];
  if (tid < 16) b3L[tid] = (tid < 12) ? b3g[tid] : 0.f;
  if (tid < 16) w4F[tid] = (tid < 12) ? W4g[tid] : 0.f;
  if (tid == 0) b4L[0] = b4g[0];
  if (tid < 12) mboxF[tid] = 0.f;
  if (tid < 3)  ctrL[tid] = -1;
  __syncthreads();

  // ---- persistent weight fragments / scalars ----
  f16x8 B1[6][2], B2[2][3], B3;
  float bias1v[6], bias2v[2], w44f[6], w47f[6];
  #pragma unroll
  for (int nt = 0; nt < 6; ++nt) {
    #pragma unroll
    for (int kt = 0; kt < 2; ++kt)
      B1[nt][kt] = *(const f16x8*)&w1B[(16 * nt + lam) * 72 + quad * 8 + 32 * kt];
    bias1v[nt] = b1L[16 * nt + lam];
    w44f[nt]   = w44L[16 * nt + lam];
    w47f[nt]   = w47L[16 * nt + lam];
  }
  #pragma unroll
  for (int nt = 0; nt < 2; ++nt) {
    #pragma unroll
    for (int kt = 0; kt < 3; ++kt)
      B2[nt][kt] = *(const f16x8*)&w2B[(16 * nt + lam) * 104 + quad * 8 + 32 * kt];
    bias2v[nt] = (16 * nt + lam < 24) ? b2L[16 * nt + lam] : 0.f;
  }
  B3 = *(const f16x8*)&w3B[lam * 32 + quad * 8];
  const float bias3v = b3L[lam];
  const float w4v    = w4F[lam];
  const float b4v    = b4L[0];

  // quad0 per-lane sliding state
  float xw[3][7], xl3[3], xtCur = 0.f, xtNext = 0.f;
  float px0 = 0.f, px1 = 0.f, px2 = 0.f, px3 = 0.f, pr2 = 0.f, pr3 = 0.f;
  float tr[3][7] = {{0}};
  float dl1 = 0.f, dl2 = 0.f, dl3 = 0.f;
  float vout = 0.f;                    // masked delta(this cell, t) after each step
  float sumsq = 0.0f;
  const int prodw = (w == 0) ? 2 : w - 1;
  f32x4 acc1[6];

  // ---- prologue: build featA(0) (only cell 0 active) + L1-stale -> acc1 ----
  {
    int i2, j2;
    const bool act2 = cellmap(0, cell, i2, j2);
    if (quad == 0 && act2) {          // cell 0: i2=0, j2=0, cold
      const float* xr = xp;
      #pragma unroll
      for (int r = 0; r < 3; ++r)
        #pragma unroll
        for (int c = 0; c < 7; ++c) xw[r][c] = xr[r * IMG + c];
      #pragma unroll
      for (int c = 0; c < 3; ++c) xl3[c] = xr[3 * IMG + c];
      xtNext = xr[3 * IMG + 3];
      px0 = xr[7]; px1 = xr[IMG + 7]; px2 = xr[2 * IMG + 7]; px3 = xr[3 * IMG + 4];
      float fx[48];
      #pragma unroll
      for (int r = 0; r < 3; ++r)
        #pragma unroll
        for (int c = 0; c < 7; ++c) fx[7 * r + c] = xw[r][c];
      fx[21] = xl3[0]; fx[22] = xl3[1]; fx[23] = xl3[2];
      #pragma unroll
      for (int q = 24; q < 48; ++q) fx[q] = 0.f;
      union { h2v p[24]; float4 v[6]; } fb;
      #pragma unroll
      for (int q = 0; q < 24; ++q) fb.p[q] = pk(fx[2 * q], fx[2 * q + 1]);
      #pragma unroll
      for (int q = 0; q < 6; ++q)
        *(float4*)&featA[cell * 72 + 8 * q] = fb.v[q];
    }
    const f16x8 A1a = *(const f16x8*)&featA[cell * 72 + quad * 8];
    const f16x8 A1b = *(const f16x8*)&featA[cell * 72 + quad * 8 + 32];
    #pragma unroll
    for (int nt = 0; nt < 6; ++nt) {
      acc1[nt] = (f32x4){bias1v[nt], bias1v[nt], bias1v[nt], bias1v[nt]};
      acc1[nt] = __builtin_amdgcn_mfma_f32_16x16x32_f16(A1a, B1[nt][0], acc1[nt], 0, 0, 0);
      acc1[nt] = __builtin_amdgcn_mfma_f32_16x16x32_f16(A1b, B1[nt][1], acc1[nt], 0, 0, 0);
    }
  }

  for (int t = 0; t < TSTEPS; ++t) {
    int i, j;
    const bool act = cellmap(t, cell, i, j);

    // ---- spin: gates age-1 data (mailbox + freshest ring cols) ----
    if (t > 0) {
      while (__hip_atomic_load(&ctrL[prodw], __ATOMIC_ACQUIRE,
                               __HIP_MEMORY_SCOPE_WORKGROUP) < t - 1) { }
    }
    const float mval = (t > 0) ? mboxF[prodw * 4 + ((t - 1) & 3)] : 0.f;

    // ---- rank-2 L1 completion + tanh + h1 stores (the fresh chain head) ----
    {
      float f47r[4], f44r[4];
      #pragma unroll
      for (int r = 0; r < 4; ++r) {
        const int m = quad * 4 + r;
        f47r[r] = __shfl(vout, m, 64);
        const float fm = __shfl(vout, m - 1, 64);
        f44r[r] = (m == 0) ? mval : fm;
      }
      #pragma unroll
      for (int nt = 0; nt < 6; ++nt) {
        #pragma unroll
        for (int r = 0; r < 4; ++r) {
          float a = acc1[nt][r];
          a = fmaf(w44f[nt], f44r[r], a);
          a = fmaf(w47f[nt], f47r[r], a);
          h1A[(16 * w + quad * 4 + r) * 104 + 16 * nt + lam] = (_Float16)fast_tanh(a);
        }
      }
    }

    // ---- L2 head: A2 reads + MFMAs (on-chain) ----
    f16x8 A2[3];
    #pragma unroll
    for (int kt = 0; kt < 3; ++kt)
      A2[kt] = *(const f16x8*)&h1A[cell * 104 + quad * 8 + 32 * kt];
    f32x4 za[2], zb[2], zc[2];
    #pragma unroll
    for (int nt = 0; nt < 2; ++nt) {
      za[nt] = (f32x4){bias2v[nt], bias2v[nt], bias2v[nt], bias2v[nt]};
      zb[nt] = (f32x4){0.f, 0.f, 0.f, 0.f};
      zc[nt] = (f32x4){0.f, 0.f, 0.f, 0.f};
      za[nt] = __builtin_amdgcn_mfma_f32_16x16x32_f16(A2[0], B2[nt][0], za[nt], 0, 0, 0);
      zb[nt] = __builtin_amdgcn_mfma_f32_16x16x32_f16(A2[1], B2[nt][1], zb[nt], 0, 0, 0);
      zc[nt] = __builtin_amdgcn_mfma_f32_16x16x32_f16(A2[2], B2[nt][2], zc[nt], 0, 0, 0);
    }

    // ---- off-chain: quad0 builds featA(t+1) (k=44,47 zeroed) ----
    int i2, j2;
    const bool act2 = cellmap(t + 1, cell, i2, j2);
    if (quad == 0 && act2) {
      if (j2 == 0) {                   // cold row start (cell inactive at t)
        const float* xr = xp + i2 * IMG;
        #pragma unroll
        for (int r = 0; r < 3; ++r)
          #pragma unroll
          for (int c = 0; c < 7; ++c) xw[r][c] = xr[r * IMG + c];
        #pragma unroll
        for (int c = 0; c < 3; ++c) xl3[c] = xr[3 * IMG + c];
        xtNext = xr[3 * IMG + 3];
        const int b0 = ((i2 - 3) & 63) * RW;
        const int b1r = ((i2 - 2) & 63) * RW;
        const int b2r = ((i2 - 1) & 63) * RW;
        #pragma unroll
        for (int c = 0; c < 7; ++c) tr[0][c] = (float)ringH[b0 + c];
        #pragma unroll
        for (int c = 0; c < 7; ++c) tr[1][c] = (float)ringH[b1r + c];
        #pragma unroll
        for (int c = 0; c < 6; ++c) tr[2][c] = (float)ringH[b2r + c];
        dl1 = dl2 = dl3 = 0.f;
        px0 = xr[7]; px1 = xr[IMG + 7]; px2 = xr[2 * IMG + 7]; px3 = xr[3 * IMG + 4];
        pr3 = (float)ringH[b0 + 7]; pr2 = (float)ringH[b1r + 7];
      } else {                         // warm slide
        if (lane == 0) tr[2][6] = mval;   // boundary fill (pre-slide)
        #pragma unroll
        for (int r = 0; r < 3; ++r) {
          #pragma unroll
          for (int c = 0; c < 6; ++c) xw[r][c] = xw[r][c + 1];
        }
        xw[0][6] = px0; xw[1][6] = px1; xw[2][6] = px2;
        xl3[0] = xl3[1]; xl3[1] = xl3[2]; xl3[2] = xtCur;
        xtNext = px3;
        #pragma unroll
        for (int r = 0; r < 3; ++r)
          #pragma unroll
          for (int c = 0; c < 6; ++c) tr[r][c] = tr[r][c + 1];
        tr[0][6] = pr3; tr[1][6] = pr2;
        if (j2 <= 184) {
          const float* xr = xp + i2 * IMG + j2;
          px0 = xr[7]; px1 = xr[IMG + 7]; px2 = xr[2 * IMG + 7]; px3 = xr[3 * IMG + 4];
          pr3 = (float)ringH[((i2 - 3) & 63) * RW + j2 + 7];
          pr2 = (float)ringH[((i2 - 2) & 63) * RW + j2 + 7];
        }
      }
      float fx[48];
      #pragma unroll
      for (int r = 0; r < 3; ++r)
        #pragma unroll
        for (int c = 0; c < 7; ++c) fx[7 * r + c] = xw[r][c];
      fx[21] = xl3[0]; fx[22] = xl3[1]; fx[23] = xl3[2];
      #pragma unroll
      for (int r = 0; r < 3; ++r)
        #pragma unroll
        for (int c = 0; c < 7; ++c) fx[24 + 7 * r + c] = tr[r][c];
      fx[44] = 0.f;                    // age-1: handled by rank-2 next iteration
      fx[45] = dl2; fx[46] = dl1;      // ages 3,2 (deltas t-2, t-1)
      fx[47] = 0.f;                    // age-1: rank-2
      union { h2v p[24]; float4 v[6]; } fb;
      #pragma unroll
      for (int q = 0; q < 24; ++q) fb.p[q] = pk(fx[2 * q], fx[2 * q + 1]);
      #pragma unroll
      for (int q = 0; q < 6; ++q)
        *(float4*)&featA[cell * 72 + 8 * q] = fb.v[q];
    }

    // ---- off-chain: L1-stale(t+1) -> acc1 (fills MFMA pipe behind L2) ----
    {
      const f16x8 A1a = *(const f16x8*)&featA[cell * 72 + quad * 8];
      const f16x8 A1b = *(const f16x8*)&featA[cell * 72 + quad * 8 + 32];
      #pragma unroll
      for (int nt = 0; nt < 6; ++nt) {
        acc1[nt] = (f32x4){bias1v[nt], bias1v[nt], bias1v[nt], bias1v[nt]};
        acc1[nt] = __builtin_amdgcn_mfma_f32_16x16x32_f16(A1a, B1[nt][0], acc1[nt], 0, 0, 0);
        acc1[nt] = __builtin_amdgcn_mfma_f32_16x16x32_f16(A1b, B1[nt][1], acc1[nt], 0, 0, 0);
      }
    }

    // ---- L2 epilogue: tanh + h2 stores ----
    #pragma unroll
    for (int nt = 0; nt < 2; ++nt) {
      const int n = 16 * nt + lam;
      if (n < 24) {
        #pragma unroll
        for (int r = 0; r < 4; ++r)
          h2A[(16 * w + quad * 4 + r) * 40 + n] =
              (_Float16)fast_tanh(za[nt][r] + zb[nt][r] + zc[nt][r]);
      }
    }

    // ---- L3 (1 MFMA) + L4 butterfly ----
    float psum;
    {
      const f16x8 A3 = *(const f16x8*)&h2A[cell * 40 + quad * 8];
      f32x4 a3 = {bias3v, bias3v, bias3v, bias3v};
      a3 = __builtin_amdgcn_mfma_f32_16x16x32_f16(A3, B3, a3, 0, 0, 0);
      f32x4 vv;
      #pragma unroll
      for (int r = 0; r < 4; ++r) vv[r] = fast_tanh(a3[r]) * w4v;
      #pragma unroll
      for (int mask = 1; mask < 16; mask <<= 1) {
        #pragma unroll
        for (int r = 0; r < 4; ++r) vv[r] += __shfl_xor(vv[r], mask, 64);
      }
      const float selLo = (lam & 1) ? vv[1] : vv[0];
      const float selHi = (lam & 1) ? vv[3] : vv[2];
      const float sel   = (lam & 2) ? selHi : selLo;
      const int src = ((lam >> 2) << 4) | (lam & 3);
      psum = __shfl(sel, src, 64);
    }

    // ---- finalize (quad0) ----
    if (quad == 0 && act) {
      const float pred = fast_tanh(psum + b4v);
      const float d = xtCur - pred;
      ringH[(i & 63) * RW + 3 + j] = (_Float16)d;
      dl3 = dl2; dl2 = dl1; dl1 = d;
      sumsq += d * d;
    }
    vout = (quad == 0 && act) ? dl1 : 0.f;     // producer-masked delta(t)
    {
      const float nv = __shfl_up(vout, 1, 64);
      if (quad == 0 && lane >= 1) tr[2][6] = nv;   // lane0 filled via mval next iter
    }
    if (quad == 0) xtCur = xtNext;
    if (lane == 15) mboxF[w * 4 + (t & 3)] = vout;
    if (lane == 0)
      __hip_atomic_store(&ctrL[w], t, __ATOMIC_RELEASE, __HIP_MEMORY_SCOPE_WORKGROUP);
  }

  // reduce sumsq (nonzero only in quad0 lanes)
  #pragma unroll
  for (int off = 32; off >= 1; off >>= 1)
    sumsq += __shfl_down(sumsq, off);
  if (lane == 0) wsum[w] = sumsq;
  __syncthreads();
  if (tid == 0) ws[blockIdx.x] = wsum[0] + wsum[1] + wsum[2];
}

__global__ void finalize_kernel(const float* __restrict__ ws, float* __restrict__ out) {
  if (threadIdx.x == 0) {
    float s = 0.0f;
    #pragma unroll
    for (int p = 0; p < NPLANES; ++p) s += ws[p];
    out[0] = sqrtf(s / 875520.0f);   // b*c*(h-2)*w = 8*3*190*192
  }
}

extern "C" void kernel_launch(void* const* d_in, const int* in_sizes, int n_in,
                              void* d_out, int out_size, void* d_ws, size_t ws_size,
                              hipStream_t stream) {
  (void)in_sizes; (void)n_in; (void)out_size; (void)ws_size;
  const float* x  = (const float*)d_in[0];
  const float* W1 = (const float*)d_in[1];
  const float* b1 = (const float*)d_in[2];
  const float* W2 = (const float*)d_in[3];
  const float* b2 = (const float*)d_in[4];
  const float* W3 = (const float*)d_in[5];
  const float* b3 = (const float*)d_in[6];
  const float* W4 = (const float*)d_in[7];
  const float* b4 = (const float*)d_in[8];
  float* ws = (float*)d_ws;

  codec_kernel<<<NPLANES, 192, 0, stream>>>(x, W1, b1, W2, b2, W3, b3, W4, b4, ws);
  finalize_kernel<<<1, 64, 0, stream>>>(ws, (float*)d_out);
}